// Round 6
// baseline (274.434 us; speedup 1.0000x reference)
//
#include <hip/hip_runtime.h>
#include <stdint.h>

typedef unsigned short u16;
typedef __bf16 bf16x8 __attribute__((ext_vector_type(8)));
typedef float f32x4 __attribute__((ext_vector_type(4)));

#define MFMA16(a, b, c) __builtin_amdgcn_mfma_f32_16x16x32_bf16(a, b, c, 0, 0, 0)

__device__ __forceinline__ float b2f(u16 u) { return __uint_as_float(((uint32_t)u) << 16); }
__device__ __forceinline__ u16 f2b(float f) {
    uint32_t x = __float_as_uint(f);
    return (u16)((x + 0x7fffu + ((x >> 16) & 1u)) >> 16);
}
// async global->LDS, 16B per lane; lds dest = wave-uniform base + lane*16
__device__ __forceinline__ void load16(const void* g, void* l) {
    __builtin_amdgcn_global_load_lds(
        (const __attribute__((address_space(1))) uint32_t*)(uintptr_t)g,
        (__attribute__((address_space(3))) uint32_t*)(uint32_t)(uintptr_t)l,
        16, 0, 0);
}
// 8 consecutive f32 -> bf16x8
__device__ __forceinline__ bf16x8 ld8f(const float* f) {
    float4 a = *(const float4*)f;
    float4 b = *(const float4*)(f + 4);
    bf16x8 o;
    o[0] = (__bf16)a.x; o[1] = (__bf16)a.y; o[2] = (__bf16)a.z; o[3] = (__bf16)a.w;
    o[4] = (__bf16)b.x; o[5] = (__bf16)b.y; o[6] = (__bf16)b.z; o[7] = (__bf16)b.w;
    return o;
}
__device__ __forceinline__ bf16x8 cvt8(float4 a, float4 b) {
    bf16x8 o;
    o[0] = (__bf16)a.x; o[1] = (__bf16)a.y; o[2] = (__bf16)a.z; o[3] = (__bf16)a.w;
    o[4] = (__bf16)b.x; o[5] = (__bf16)b.y; o[6] = (__bf16)b.z; o[7] = (__bf16)b.w;
    return o;
}

// ---------------------------------------------------------------------------
// Kernel 0: f32 -> bf16 conversion of the four weight matrices. grid (512, 4).
// ---------------------------------------------------------------------------
__global__ __launch_bounds__(256) void convert_k(
    const float* __restrict__ Wq, const float* __restrict__ Wk,
    const float* __restrict__ Wv, const float* __restrict__ Wo,
    u16* __restrict__ wqb, u16* __restrict__ wkb, u16* __restrict__ wvb,
    u16* __restrict__ wob)
{
    const float* src; u16* dst;
    switch (blockIdx.y) {
        case 0:  src = Wq; dst = wqb; break;
        case 1:  src = Wk; dst = wkb; break;
        case 2:  src = Wv; dst = wvb; break;
        default: src = Wo; dst = wob; break;
    }
    int i = blockIdx.x * 256 + threadIdx.x;   // 131072 chunks of 8
    bf16x8 o = ld8f(src + (size_t)i * 8);
    *(bf16x8*)(dst + (size_t)i * 8) = o;
}

// ---------------------------------------------------------------------------
// Kernel 1: QKV projection + bias + RoPE + head split.
// 64x128 tiles, grid (24, 64); A (f32) reg-staged with convert, W (bf16) via
// global_load_lds. Single barrier per K-tile, LDS double-buffered.
// qh,kh: (B,H,L,64) bf16 ; vt: (B,H,64,L) bf16
// ---------------------------------------------------------------------------
__global__ __launch_bounds__(256, 5) void gemm_proj_b(
    const float* __restrict__ qf, const float* __restrict__ kf, const float* __restrict__ vf,
    const u16* __restrict__ wqb, const u16* __restrict__ wkb, const u16* __restrict__ wvb,
    const float* __restrict__ bq, const float* __restrict__ bk, const float* __restrict__ bv,
    const float* __restrict__ sin_enc,
    u16* __restrict__ qh, u16* __restrict__ kh, u16* __restrict__ vt)
{
    __shared__ __align__(16) u16 lA[2][64 * 32];    // 4 KB each
    __shared__ __align__(16) u16 lB[2][128 * 32];   // 8 KB each
    const int t = threadIdx.x, wave = t >> 6, lane = t & 63;
    const int bx = blockIdx.x;
    const int w_idx = bx >> 3;
    const int n0 = (bx & 7) << 7;
    const int m0 = blockIdx.y << 6;
    const float* A = (w_idx == 0) ? qf : (w_idx == 1 ? kf : vf);
    const u16*   W = (w_idx == 0) ? wqb : (w_idx == 1 ? wkb : wvb);
    const float* bias = (w_idx == 0) ? bq : (w_idx == 1 ? bk : bv);

    const int wr = wave >> 1, wc = wave & 1;        // 2x2 wave quadrants
    const int col16 = lane & 15, g16 = lane >> 4;
    f32x4 acc[2][4] = {};

    // A staging (reg path): thread t -> chunk t: row t>>2, k-phase (t&3)*8
    const float* gA = A + (size_t)(m0 + (t >> 2)) * 1024 + ((t & 3) << 3);
    u16* wA0 = lA[0] + t * 8;
    u16* wA1 = lA[1] + t * 8;
    // B staging (load16): chunks c0 = wave*128+lane (row c>>2), c1 = c0+64
    const int c0 = wave * 128 + lane;
    const u16* gB = W + (size_t)(n0 + (c0 >> 2)) * 1024 + ((c0 & 3) << 3);

    // pre-loop: tile 0 into buf0; prefetch tile-1 A regs
    float4 ra0 = *(const float4*)(gA);
    float4 ra1 = *(const float4*)(gA + 4);
    load16(gB, (char*)lB[0] + wave * 2048);
    load16(gB + 16 * 1024, (char*)lB[0] + wave * 2048 + 1024);
    *(bf16x8*)wA0 = cvt8(ra0, ra1);
    ra0 = *(const float4*)(gA + 32);
    ra1 = *(const float4*)(gA + 36);

    for (int it = 0; it < 32; ++it) {
        const int buf = it & 1, nbuf = buf ^ 1;
        __syncthreads();    // tile-it staging (LDS writes + load16) complete & visible
        if (it + 1 < 32) {  // stage tile it+1 into nbuf (regs hold tile it+1)
            *(bf16x8*)(nbuf ? wA1 : wA0) = cvt8(ra0, ra1);
            const int kk = (it + 1) << 5;
            load16(gB + kk, (char*)lB[nbuf] + wave * 2048);
            load16(gB + kk + 16 * 1024, (char*)lB[nbuf] + wave * 2048 + 1024);
            if (it + 2 < 32) {
                ra0 = *(const float4*)(gA + (it + 2) * 32);
                ra1 = *(const float4*)(gA + (it + 2) * 32 + 4);
            }
        }
        // compute tile it from buf
        const u16* pA = lA[buf] + (wr * 32 + col16) * 32 + g16 * 8;
        const u16* pB = lB[buf] + (wc * 64 + col16) * 32 + g16 * 8;
        bf16x8 af[2], bfr[4];
#pragma unroll
        for (int i = 0; i < 2; i++) af[i] = *(const bf16x8*)(pA + i * 512);
#pragma unroll
        for (int i = 0; i < 4; i++) bfr[i] = *(const bf16x8*)(pB + i * 512);
#pragma unroll
        for (int mi = 0; mi < 2; mi++)
#pragma unroll
            for (int ni = 0; ni < 4; ni++)
                acc[mi][ni] = MFMA16(af[mi], bfr[ni], acc[mi][ni]);
    }

    // epilogue: bias + rope(+scale for Q) + head-split store
#pragma unroll
    for (int ni = 0; ni < 4; ni++) {
        const int n = n0 + wc * 64 + ni * 16 + col16;
        const float bn = bias[n];
        const int h = n >> 6, hd = n & 63;
#pragma unroll
        for (int mi = 0; mi < 2; mi++) {
#pragma unroll
            for (int r = 0; r < 4; r++) {
                const int m = m0 + wr * 32 + mi * 16 + g16 * 4 + r;
                const int b = m >> 9, l = m & 511;
                float x = acc[mi][ni][r] + bn;
                if (w_idx == 2) {
                    vt[((size_t)(b * 16 + h) * 64 + hd) * 512 + l] = f2b(x);
                } else {
                    float partner = __shfl_xor(x, 1);
                    float s = sin_enc[(size_t)l * 1024 + (n & ~1)];
                    float c = sin_enc[(size_t)l * 1024 + (n | 1)];
                    float y = (n & 1) ? (x * c + partner * s) : (x * c - partner * s);
                    if (w_idx == 0) y *= 0.125f;
                    u16* dst = (w_idx == 0) ? qh : kh;
                    dst[((size_t)(b * 16 + h) * 512 + l) * 64 + hd] = f2b(y);
                }
            }
        }
    }
}

// ---------------------------------------------------------------------------
// Kernel 1 (fallback, ws < 64 MiB): f32 staging path (round-3, verified).
// ---------------------------------------------------------------------------
__global__ __launch_bounds__(256) void gemm_proj_f32(
    const float* __restrict__ qin, const float* __restrict__ kin, const float* __restrict__ vin,
    const float* __restrict__ Wq, const float* __restrict__ bq,
    const float* __restrict__ Wk, const float* __restrict__ bk,
    const float* __restrict__ Wv, const float* __restrict__ bv,
    const float* __restrict__ sin_enc,
    u16* __restrict__ qh, u16* __restrict__ kh, u16* __restrict__ vt)
{
    __shared__ __align__(16) u16 lA[128 * 32];
    __shared__ __align__(16) u16 lB[128 * 32];
    const int t = threadIdx.x, wave = t >> 6, lane = t & 63;
    const int bx = blockIdx.x;
    const int w_idx = bx >> 3;
    const int n0 = (bx & 7) << 7;
    const int m0 = blockIdx.y << 7;
    const float* A    = (w_idx == 0) ? qin : (w_idx == 1 ? kin : vin);
    const float* W    = (w_idx == 0) ? Wq  : (w_idx == 1 ? Wk  : Wv);
    const float* bias = (w_idx == 0) ? bq  : (w_idx == 1 ? bk  : bv);

    const int wr = wave >> 1, wc = wave & 1;
    const int col16 = lane & 15, g16 = lane >> 4;
    f32x4 acc[4][4] = {};

    const int c0   = wave * 128 + lane;
    const int row0 = c0 >> 2;
    const int kp   = (c0 & 3) << 3;
    const size_t gA0 = (size_t)(m0 + row0) * 1024 + kp;
    const size_t gB0 = (size_t)(n0 + row0) * 1024 + kp;
    u16* wA0 = lA + c0 * 8;
    u16* wA1 = lA + (c0 + 64) * 8;
    u16* wB0 = lB + c0 * 8;
    u16* wB1 = lB + (c0 + 64) * 8;

    bf16x8 ra0 = ld8f(A + gA0);
    bf16x8 ra1 = ld8f(A + gA0 + 16 * 1024);
    bf16x8 rb0 = ld8f(W + gB0);
    bf16x8 rb1 = ld8f(W + gB0 + 16 * 1024);

    for (int kk = 32; kk <= 1024; kk += 32) {
        __syncthreads();
        *(bf16x8*)wA0 = ra0; *(bf16x8*)wA1 = ra1;
        *(bf16x8*)wB0 = rb0; *(bf16x8*)wB1 = rb1;
        __syncthreads();
        if (kk < 1024) {
            ra0 = ld8f(A + gA0 + kk);
            ra1 = ld8f(A + gA0 + kk + 16 * 1024);
            rb0 = ld8f(W + gB0 + kk);
            rb1 = ld8f(W + gB0 + kk + 16 * 1024);
        }
        const u16* pA = lA + (wr * 64 + col16) * 32 + g16 * 8;
        const u16* pB = lB + (wc * 64 + col16) * 32 + g16 * 8;
        bf16x8 af[4], bfr[4];
#pragma unroll
        for (int i = 0; i < 4; i++) {
            af[i]  = *(const bf16x8*)(pA + i * 512);
            bfr[i] = *(const bf16x8*)(pB + i * 512);
        }
#pragma unroll
        for (int mi = 0; mi < 4; mi++)
#pragma unroll
            for (int ni = 0; ni < 4; ni++)
                acc[mi][ni] = MFMA16(af[mi], bfr[ni], acc[mi][ni]);
    }

#pragma unroll
    for (int ni = 0; ni < 4; ni++) {
        const int n = n0 + wc * 64 + ni * 16 + col16;
        const float bn = bias[n];
        const int h = n >> 6, hd = n & 63;
#pragma unroll
        for (int mi = 0; mi < 4; mi++) {
#pragma unroll
            for (int r = 0; r < 4; r++) {
                const int m = m0 + wr * 64 + mi * 16 + g16 * 4 + r;
                const int b = m >> 9, l = m & 511;
                float x = acc[mi][ni][r] + bn;
                if (w_idx == 2) {
                    vt[((size_t)(b * 16 + h) * 64 + hd) * 512 + l] = f2b(x);
                } else {
                    float partner = __shfl_xor(x, 1);
                    float s = sin_enc[(size_t)l * 1024 + (n & ~1)];
                    float c = sin_enc[(size_t)l * 1024 + (n | 1)];
                    float y = (n & 1) ? (x * c + partner * s) : (x * c - partner * s);
                    if (w_idx == 0) y *= 0.125f;
                    u16* dst = (w_idx == 0) ? qh : kh;
                    dst[((size_t)(b * 16 + h) * 512 + l) * 64 + hd] = f2b(y);
                }
            }
        }
    }
}

// ---------------------------------------------------------------------------
// Kernel 2: flash attention with dist bias + key mask.
// Grid 1024, 256 thr. dist staged via coalesced int4 -> u8 LDS tile.
// ---------------------------------------------------------------------------
__global__ __launch_bounds__(256) void attn_kernel(
    const u16* __restrict__ qh, const u16* __restrict__ kh, const u16* __restrict__ vt,
    const float* __restrict__ demb_g, const int* __restrict__ length,
    const int* __restrict__ dist, u16* __restrict__ ctx)
{
    __shared__ __align__(16) u16 Qs[64 * 64];
    __shared__ __align__(16) u16 Ks[64 * 64];
    __shared__ __align__(16) u16 Vs[64 * 64];
    __shared__ __align__(16) u16 Ps[4][16 * 64];
    __shared__ __align__(16) uint8_t Ds[64 * 64];
    __shared__ float demb[64];

    const int t = threadIdx.x, wave = t >> 6, lane = t & 63;
    const int bxx = blockIdx.x;
    const int qt = bxx & 7, bh = bxx >> 3;
    const int b = bh >> 4, h = bh & 15;
    if (t < 64) demb[t] = demb_g[t * 16 + h];
    const int len_b = length[b];
    const int ktmax = (len_b + 63) >> 6;
    const int col16 = lane & 15, g16 = lane >> 4;
    const int c0 = wave * 128 + lane, c1 = c0 + 64;

    const u16* qbase = qh + (size_t)(bh * 512 + qt * 64) * 64;
    {
        uint4 rq0 = *(const uint4*)(qbase + c0 * 8);
        uint4 rq1 = *(const uint4*)(qbase + c1 * 8);
        *(uint4*)((char*)Qs + c0 * 16) = rq0;
        *(uint4*)((char*)Qs + c1 * 16) = rq1;
    }

    const u16* kbase = kh + (size_t)bh * 512 * 64;
    const u16* vbase = vt + (size_t)bh * 64 * 512;
    const int qrow_base = qt * 64 + wave * 16 + g16 * 4;

    const int drow = t >> 2;
    const int dcol = (t & 3) << 4;
    const int* dg = dist + (size_t)b * 512 * 512 + (size_t)(qt * 64 + drow) * 512 + dcol;
    uint32_t* DsW = (uint32_t*)(Ds + drow * 64 + dcol);

    uint4 rk0 = *(const uint4*)(kbase + c0 * 8);
    uint4 rk1 = *(const uint4*)(kbase + c1 * 8);
    uint4 rv0 = *(const uint4*)(vbase + (size_t)(c0 >> 3) * 512 + (c0 & 7) * 8);
    uint4 rv1 = *(const uint4*)(vbase + (size_t)(c1 >> 3) * 512 + (c1 & 7) * 8);
    int4 dd[4];
#pragma unroll
    for (int j = 0; j < 4; j++) dd[j] = *(const int4*)(dg + j * 4);

    __syncthreads();
    const u16* pQ = Qs + (wave * 16 + col16) * 64 + g16 * 8;
    const bf16x8 qa0 = *(const bf16x8*)pQ;
    const bf16x8 qa1 = *(const bf16x8*)(pQ + 32);

    f32x4 oacc[4] = {};
    float mrow[4], lrow[4];
#pragma unroll
    for (int r = 0; r < 4; r++) { mrow[r] = -1e30f; lrow[r] = 0.f; }

    for (int kt = 0; kt < ktmax; kt++) {
        __syncthreads();
        *(uint4*)((char*)Ks + c0 * 16) = rk0;
        *(uint4*)((char*)Ks + c1 * 16) = rk1;
        *(uint4*)((char*)Vs + c0 * 16) = rv0;
        *(uint4*)((char*)Vs + c1 * 16) = rv1;
#pragma unroll
        for (int j = 0; j < 4; j++)
            DsW[j] = (uint32_t)(dd[j].x & 63) | ((uint32_t)(dd[j].y & 63) << 8) |
                     ((uint32_t)(dd[j].z & 63) << 16) | ((uint32_t)(dd[j].w & 63) << 24);
        __syncthreads();
        if (kt + 1 < ktmax) {
            const u16* kb = kbase + (size_t)(kt + 1) * 64 * 64;
            rk0 = *(const uint4*)(kb + c0 * 8);
            rk1 = *(const uint4*)(kb + c1 * 8);
            rv0 = *(const uint4*)(vbase + (size_t)(c0 >> 3) * 512 + (kt + 1) * 64 + (c0 & 7) * 8);
            rv1 = *(const uint4*)(vbase + (size_t)(c1 >> 3) * 512 + (kt + 1) * 64 + (c1 & 7) * 8);
            const int* dgn = dg + (kt + 1) * 64;
#pragma unroll
            for (int j = 0; j < 4; j++) dd[j] = *(const int4*)(dgn + j * 4);
        }

        f32x4 sacc[4] = {};
#pragma unroll
        for (int ni = 0; ni < 4; ni++) {
            const u16* pK = Ks + (ni * 16 + col16) * 64 + g16 * 8;
            bf16x8 kf0 = *(const bf16x8*)pK;
            bf16x8 kf1 = *(const bf16x8*)(pK + 32);
            sacc[ni] = MFMA16(qa0, kf0, sacc[ni]);
            sacc[ni] = MFMA16(qa1, kf1, sacc[ni]);
        }

        float rmax[4] = {-1e30f, -1e30f, -1e30f, -1e30f};
        const int qrl = wave * 16 + g16 * 4;
#pragma unroll
        for (int ni = 0; ni < 4; ni++) {
            const int kcl = ni * 16 + col16;
            const bool masked = (kt * 64 + kcl) >= len_b;
#pragma unroll
            for (int r = 0; r < 4; r++) {
                float s = sacc[ni][r] + demb[Ds[(qrl + r) * 64 + kcl]];
                s = masked ? -1e9f : s;
                sacc[ni][r] = s;
                rmax[r] = fmaxf(rmax[r], s);
            }
        }
#pragma unroll
        for (int off = 1; off < 16; off <<= 1)
#pragma unroll
            for (int r = 0; r < 4; r++) rmax[r] = fmaxf(rmax[r], __shfl_xor(rmax[r], off));

        float alpha[4], rsum[4];
#pragma unroll
        for (int r = 0; r < 4; r++) {
            float mn = fmaxf(mrow[r], rmax[r]);
            alpha[r] = __expf(mrow[r] - mn);
            mrow[r] = mn;
            rsum[r] = 0.f;
        }
#pragma unroll
        for (int ni = 0; ni < 4; ni++)
#pragma unroll
            for (int r = 0; r < 4; r++) {
                float p = __expf(sacc[ni][r] - mrow[r]);
                sacc[ni][r] = p;
                rsum[r] += p;
            }
#pragma unroll
        for (int off = 1; off < 16; off <<= 1)
#pragma unroll
            for (int r = 0; r < 4; r++) rsum[r] += __shfl_xor(rsum[r], off);
#pragma unroll
        for (int r = 0; r < 4; r++) lrow[r] = lrow[r] * alpha[r] + rsum[r];
#pragma unroll
        for (int di = 0; di < 4; di++)
#pragma unroll
            for (int r = 0; r < 4; r++) oacc[di][r] *= alpha[r];

        u16* Pw = &Ps[wave][0];
#pragma unroll
        for (int ni = 0; ni < 4; ni++)
#pragma unroll
            for (int r = 0; r < 4; r++)
                Pw[(g16 * 4 + r) * 64 + ni * 16 + col16] = f2b(sacc[ni][r]);
        __syncthreads();

        const u16* pP = Pw + col16 * 64 + g16 * 8;
        bf16x8 pa0 = *(const bf16x8*)pP;
        bf16x8 pa1 = *(const bf16x8*)(pP + 32);
#pragma unroll
        for (int di = 0; di < 4; di++) {
            const u16* pV = Vs + (di * 16 + col16) * 64 + g16 * 8;
            bf16x8 vf0 = *(const bf16x8*)pV;
            bf16x8 vf1 = *(const bf16x8*)(pV + 32);
            oacc[di] = MFMA16(pa0, vf0, oacc[di]);
            oacc[di] = MFMA16(pa1, vf1, oacc[di]);
        }
    }

#pragma unroll
    for (int di = 0; di < 4; di++)
#pragma unroll
        for (int r = 0; r < 4; r++) {
            const int qrow = qrow_base + r;
            const int d = di * 16 + col16;
            const float inv_l = 1.0f / fmaxf(lrow[r], 1e-30f);
            ctx[(size_t)(b * 512 + qrow) * 1024 + h * 64 + d] = f2b(oacc[di][r] * inv_l);
        }
}

// ---------------------------------------------------------------------------
// Kernel 3: ctx(bf16) @ Wo^T(bf16) + bo -> f32. 64x64 tiles, grid (16,64),
// single-barrier dbuf, all global_load_lds.
// ---------------------------------------------------------------------------
__global__ __launch_bounds__(256, 4) void gemm_out_b(
    const u16* __restrict__ ctx, const u16* __restrict__ wob,
    const float* __restrict__ bo, float* __restrict__ out)
{
    __shared__ __align__(16) u16 lA[2][64 * 32];
    __shared__ __align__(16) u16 lB[2][64 * 32];
    const int t = threadIdx.x, wave = t >> 6, lane = t & 63;
    const int n0 = blockIdx.x << 6;
    const int m0 = blockIdx.y << 6;
    const int wr = wave >> 1, wc = wave & 1;
    const int col16 = lane & 15, g16 = lane >> 4;
    f32x4 acc[2][2] = {};

    // 256 chunks per tile, 1/thread: wave w covers chunks w*64+lane
    const int cA = wave * 64 + lane;
    const u16* gA = ctx + (size_t)(m0 + (cA >> 2)) * 1024 + ((cA & 3) << 3);
    const u16* gB = wob + (size_t)(n0 + (cA >> 2)) * 1024 + ((cA & 3) << 3);

    load16(gA, (char*)lA[0] + wave * 1024);
    load16(gB, (char*)lB[0] + wave * 1024);

    for (int it = 0; it < 32; ++it) {
        const int buf = it & 1, nbuf = buf ^ 1;
        __syncthreads();
        if (it + 1 < 32) {
            const int kk = (it + 1) << 5;
            load16(gA + kk, (char*)lA[nbuf] + wave * 1024);
            load16(gB + kk, (char*)lB[nbuf] + wave * 1024);
        }
        const u16* pA = lA[buf] + (wr * 32 + col16) * 32 + g16 * 8;
        const u16* pB = lB[buf] + (wc * 32 + col16) * 32 + g16 * 8;
        bf16x8 af[2], bfr[2];
#pragma unroll
        for (int i = 0; i < 2; i++) {
            af[i]  = *(const bf16x8*)(pA + i * 512);
            bfr[i] = *(const bf16x8*)(pB + i * 512);
        }
#pragma unroll
        for (int mi = 0; mi < 2; mi++)
#pragma unroll
            for (int ni = 0; ni < 2; ni++)
                acc[mi][ni] = MFMA16(af[mi], bfr[ni], acc[mi][ni]);
    }

#pragma unroll
    for (int ni = 0; ni < 2; ni++) {
        const int n = n0 + wc * 32 + ni * 16 + col16;
        const float bn = bo[n];
#pragma unroll
        for (int mi = 0; mi < 2; mi++)
#pragma unroll
            for (int r = 0; r < 4; r++) {
                const int m = m0 + wr * 32 + mi * 16 + g16 * 4 + r;
                out[(size_t)m * 1024 + n] = acc[mi][ni][r] + bn;
            }
    }
}

// ---------------------------------------------------------------------------
// Kernel 3 (fallback): ctx(bf16) @ Wo^T(f32) + bo -> f32 (round-3 path).
// ---------------------------------------------------------------------------
__global__ __launch_bounds__(256) void gemm_out_f32(
    const u16* __restrict__ ctx, const float* __restrict__ Wo,
    const float* __restrict__ bo, float* __restrict__ out)
{
    __shared__ __align__(16) u16 lA[128 * 32];
    __shared__ __align__(16) u16 lB[128 * 32];
    const int t = threadIdx.x, wave = t >> 6, lane = t & 63;
    const int n0 = blockIdx.x << 7;
    const int m0 = blockIdx.y << 7;
    const int wr = wave >> 1, wc = wave & 1;
    const int col16 = lane & 15, g16 = lane >> 4;
    f32x4 acc[4][4] = {};

    const int c0   = wave * 128 + lane;
    const int row0 = c0 >> 2;
    const int kp   = (c0 & 3) << 3;
    const u16* gA = ctx + (size_t)(m0 + row0) * 1024 + kp;
    const size_t gB0 = (size_t)(n0 + row0) * 1024 + kp;
    u16* wA0 = lA + c0 * 8;
    u16* wA1 = lA + (c0 + 64) * 8;
    u16* wB0 = lB + c0 * 8;
    u16* wB1 = lB + (c0 + 64) * 8;

    uint4 ua0 = *(const uint4*)gA;
    uint4 ua1 = *(const uint4*)(gA + 16 * 1024);
    bf16x8 ra0 = *(bf16x8*)&ua0, ra1 = *(bf16x8*)&ua1;
    bf16x8 rb0 = ld8f(Wo + gB0);
    bf16x8 rb1 = ld8f(Wo + gB0 + 16 * 1024);

    for (int kk = 32; kk <= 1024; kk += 32) {
        __syncthreads();
        *(bf16x8*)wA0 = ra0; *(bf16x8*)wA1 = ra1;
        *(bf16x8*)wB0 = rb0; *(bf16x8*)wB1 = rb1;
        __syncthreads();
        if (kk < 1024) {
            uint4 t0 = *(const uint4*)(gA + kk);
            uint4 t1 = *(const uint4*)(gA + kk + 16 * 1024);
            ra0 = *(bf16x8*)&t0; ra1 = *(bf16x8*)&t1;
            rb0 = ld8f(Wo + gB0 + kk);
            rb1 = ld8f(Wo + gB0 + kk + 16 * 1024);
        }
        const u16* pA = lA + (wr * 64 + col16) * 32 + g16 * 8;
        const u16* pB = lB + (wc * 64 + col16) * 32 + g16 * 8;
        bf16x8 af[4], bfr[4];
#pragma unroll
        for (int i = 0; i < 4; i++) {
            af[i]  = *(const bf16x8*)(pA + i * 512);
            bfr[i] = *(const bf16x8*)(pB + i * 512);
        }
#pragma unroll
        for (int mi = 0; mi < 4; mi++)
#pragma unroll
            for (int ni = 0; ni < 4; ni++)
                acc[mi][ni] = MFMA16(af[mi], bfr[ni], acc[mi][ni]);
    }

#pragma unroll
    for (int ni = 0; ni < 4; ni++) {
        const int n = n0 + wc * 64 + ni * 16 + col16;
        const float bn = bo[n];
#pragma unroll
        for (int mi = 0; mi < 4; mi++)
#pragma unroll
            for (int r = 0; r < 4; r++) {
                const int m = m0 + wr * 64 + mi * 16 + g16 * 4 + r;
                out[(size_t)m * 1024 + n] = acc[mi][ni][r] + bn;
            }
    }
}

extern "C" void kernel_launch(void* const* d_in, const int* in_sizes, int n_in,
                              void* d_out, int out_size, void* d_ws, size_t ws_size,
                              hipStream_t stream) {
    const float* q       = (const float*)d_in[0];
    const float* k       = (const float*)d_in[1];
    const float* v       = (const float*)d_in[2];
    const float* Wq      = (const float*)d_in[3];
    const float* bq      = (const float*)d_in[4];
    const float* Wk      = (const float*)d_in[5];
    const float* bk      = (const float*)d_in[6];
    const float* Wv      = (const float*)d_in[7];
    const float* bv      = (const float*)d_in[8];
    const float* Wo      = (const float*)d_in[9];
    const float* bo      = (const float*)d_in[10];
    const float* demb    = (const float*)d_in[11];
    const float* sin_enc = (const float*)d_in[12];
    const int* length    = (const int*)d_in[13];
    const int* dist      = (const int*)d_in[14];

    const size_t SLOT = 4194304;          // 8 MiB region, in u16 elements
    u16* qh  = (u16*)d_ws;
    u16* kh  = qh + SLOT;
    u16* vt  = kh + SLOT;
    u16* ctx = vt + SLOT;

    if (ws_size >= (size_t)64 * 1024 * 1024) {
        u16* wqb = ctx + SLOT;            // 4 x 2 MiB weight regions
        u16* wkb = wqb + 1048576;
        u16* wvb = wkb + 1048576;
        u16* wob = wvb + 1048576;
        convert_k<<<dim3(512, 4), 256, 0, stream>>>(Wq, Wk, Wv, Wo, wqb, wkb, wvb, wob);
        gemm_proj_b<<<dim3(24, 64), 256, 0, stream>>>(q, k, v, wqb, wkb, wvb,
                                                      bq, bk, bv, sin_enc, qh, kh, vt);
        attn_kernel<<<dim3(1024), 256, 0, stream>>>(qh, kh, vt, demb, length, dist, ctx);
        gemm_out_b<<<dim3(16, 64), 256, 0, stream>>>(ctx, wob, bo, (float*)d_out);
    } else {
        gemm_proj_f32<<<dim3(24, 32), 256, 0, stream>>>(q, k, v, Wq, bq, Wk, bk, Wv, bv,
                                                        sin_enc, qh, kh, vt);
        attn_kernel<<<dim3(1024), 256, 0, stream>>>(qh, kh, vt, demb, length, dist, ctx);
        gemm_out_f32<<<dim3(8, 32), 256, 0, stream>>>(ctx, Wo, bo, (float*)d_out);
    }
}

// Round 7
// 267.447 us; speedup vs baseline: 1.0261x; 1.0261x over previous
//
#include <hip/hip_runtime.h>
#include <stdint.h>

typedef unsigned short u16;
typedef __bf16 bf16x8 __attribute__((ext_vector_type(8)));
typedef float f32x4 __attribute__((ext_vector_type(4)));

#define MFMA16(a, b, c) __builtin_amdgcn_mfma_f32_16x16x32_bf16(a, b, c, 0, 0, 0)

__device__ __forceinline__ float b2f(u16 u) { return __uint_as_float(((uint32_t)u) << 16); }
__device__ __forceinline__ u16 f2b(float f) {
    uint32_t x = __float_as_uint(f);
    return (u16)((x + 0x7fffu + ((x >> 16) & 1u)) >> 16);
}
// async global->LDS, 16B per lane; lds dest = wave-uniform base + lane*16
__device__ __forceinline__ void load16(const void* g, void* l) {
    __builtin_amdgcn_global_load_lds(
        (const __attribute__((address_space(1))) uint32_t*)(uintptr_t)g,
        (__attribute__((address_space(3))) uint32_t*)(uint32_t)(uintptr_t)l,
        16, 0, 0);
}
// 8 consecutive f32 -> bf16x8
__device__ __forceinline__ bf16x8 ld8f(const float* f) {
    float4 a = *(const float4*)f;
    float4 b = *(const float4*)(f + 4);
    bf16x8 o;
    o[0] = (__bf16)a.x; o[1] = (__bf16)a.y; o[2] = (__bf16)a.z; o[3] = (__bf16)a.w;
    o[4] = (__bf16)b.x; o[5] = (__bf16)b.y; o[6] = (__bf16)b.z; o[7] = (__bf16)b.w;
    return o;
}
__device__ __forceinline__ bf16x8 cvt8(float4 a, float4 b) {
    bf16x8 o;
    o[0] = (__bf16)a.x; o[1] = (__bf16)a.y; o[2] = (__bf16)a.z; o[3] = (__bf16)a.w;
    o[4] = (__bf16)b.x; o[5] = (__bf16)b.y; o[6] = (__bf16)b.z; o[7] = (__bf16)b.w;
    return o;
}

// ---------------------------------------------------------------------------
// Kernel 0: f32 -> bf16 conversion of the four weight matrices. grid (512, 4).
// ---------------------------------------------------------------------------
__global__ __launch_bounds__(256) void convert_k(
    const float* __restrict__ Wq, const float* __restrict__ Wk,
    const float* __restrict__ Wv, const float* __restrict__ Wo,
    u16* __restrict__ wqb, u16* __restrict__ wkb, u16* __restrict__ wvb,
    u16* __restrict__ wob)
{
    const float* src; u16* dst;
    switch (blockIdx.y) {
        case 0:  src = Wq; dst = wqb; break;
        case 1:  src = Wk; dst = wkb; break;
        case 2:  src = Wv; dst = wvb; break;
        default: src = Wo; dst = wob; break;
    }
    int i = blockIdx.x * 256 + threadIdx.x;   // 131072 chunks of 8
    bf16x8 o = ld8f(src + (size_t)i * 8);
    *(bf16x8*)(dst + (size_t)i * 8) = o;
}

// ---------------------------------------------------------------------------
// Kernel 1: QKV projection + bias + RoPE + head split.
// 64x128 tiles. Grid (192, 8): x = (w_idx, m-tile) group, y = n-tile.
// Linear block id = x + y*192, 192 % 8 == 0 -> all 8 n-tiles of a group land
// on the SAME XCD (round-robin dispatch), so the f32 A-tile is fetched from
// HBM once per group and served from that XCD's L2 for the other 7 blocks.
// A (f32) reg-staged with convert, W (bf16) via global_load_lds; single
// barrier per K-tile, LDS double-buffered.
// ---------------------------------------------------------------------------
__global__ __launch_bounds__(256, 6) void gemm_proj_b(
    const float* __restrict__ qf, const float* __restrict__ kf, const float* __restrict__ vf,
    const u16* __restrict__ wqb, const u16* __restrict__ wkb, const u16* __restrict__ wvb,
    const float* __restrict__ bq, const float* __restrict__ bk, const float* __restrict__ bv,
    const float* __restrict__ sin_enc,
    u16* __restrict__ qh, u16* __restrict__ kh, u16* __restrict__ vt)
{
    __shared__ __align__(16) u16 lA[2][64 * 32];    // 4 KB each
    __shared__ __align__(16) u16 lB[2][128 * 32];   // 8 KB each
    const int t = threadIdx.x, wave = t >> 6, lane = t & 63;
    const int group = blockIdx.x;          // 0..191
    const int w_idx = group >> 6;          // 0..2 (Q/K/V)
    const int m0 = (group & 63) << 6;      // m-tile
    const int n0 = blockIdx.y << 7;        // n-tile
    const float* A = (w_idx == 0) ? qf : (w_idx == 1 ? kf : vf);
    const u16*   W = (w_idx == 0) ? wqb : (w_idx == 1 ? wkb : wvb);
    const float* bias = (w_idx == 0) ? bq : (w_idx == 1 ? bk : bv);

    const int wr = wave >> 1, wc = wave & 1;        // 2x2 wave quadrants
    const int col16 = lane & 15, g16 = lane >> 4;
    f32x4 acc[2][4] = {};

    // A staging (reg path): thread t -> chunk t: row t>>2, k-phase (t&3)*8
    const float* gA = A + (size_t)(m0 + (t >> 2)) * 1024 + ((t & 3) << 3);
    u16* wA0 = lA[0] + t * 8;
    u16* wA1 = lA[1] + t * 8;
    // B staging (load16): chunks c0 = wave*128+lane (row c>>2), c1 = c0+64
    const int c0 = wave * 128 + lane;
    const u16* gB = W + (size_t)(n0 + (c0 >> 2)) * 1024 + ((c0 & 3) << 3);

    // pre-loop: tile 0 into buf0; prefetch tile-1 A regs
    float4 ra0 = *(const float4*)(gA);
    float4 ra1 = *(const float4*)(gA + 4);
    load16(gB, (char*)lB[0] + wave * 2048);
    load16(gB + 16 * 1024, (char*)lB[0] + wave * 2048 + 1024);
    *(bf16x8*)wA0 = cvt8(ra0, ra1);
    ra0 = *(const float4*)(gA + 32);
    ra1 = *(const float4*)(gA + 36);

    for (int it = 0; it < 32; ++it) {
        const int buf = it & 1, nbuf = buf ^ 1;
        __syncthreads();    // tile-it staging (LDS writes + load16) complete & visible
        if (it + 1 < 32) {  // stage tile it+1 into nbuf (regs hold tile it+1)
            *(bf16x8*)(nbuf ? wA1 : wA0) = cvt8(ra0, ra1);
            const int kk = (it + 1) << 5;
            load16(gB + kk, (char*)lB[nbuf] + wave * 2048);
            load16(gB + kk + 16 * 1024, (char*)lB[nbuf] + wave * 2048 + 1024);
            if (it + 2 < 32) {
                ra0 = *(const float4*)(gA + (it + 2) * 32);
                ra1 = *(const float4*)(gA + (it + 2) * 32 + 4);
            }
        }
        // compute tile it from buf
        const u16* pA = lA[buf] + (wr * 32 + col16) * 32 + g16 * 8;
        const u16* pB = lB[buf] + (wc * 64 + col16) * 32 + g16 * 8;
        bf16x8 af[2], bfr[4];
#pragma unroll
        for (int i = 0; i < 2; i++) af[i] = *(const bf16x8*)(pA + i * 512);
#pragma unroll
        for (int i = 0; i < 4; i++) bfr[i] = *(const bf16x8*)(pB + i * 512);
#pragma unroll
        for (int mi = 0; mi < 2; mi++)
#pragma unroll
            for (int ni = 0; ni < 4; ni++)
                acc[mi][ni] = MFMA16(af[mi], bfr[ni], acc[mi][ni]);
    }

    // epilogue: bias + rope(+scale for Q) + head-split store
#pragma unroll
    for (int ni = 0; ni < 4; ni++) {
        const int n = n0 + wc * 64 + ni * 16 + col16;
        const float bn = bias[n];
        const int h = n >> 6, hd = n & 63;
#pragma unroll
        for (int mi = 0; mi < 2; mi++) {
#pragma unroll
            for (int r = 0; r < 4; r++) {
                const int m = m0 + wr * 32 + mi * 16 + g16 * 4 + r;
                const int b = m >> 9, l = m & 511;
                float x = acc[mi][ni][r] + bn;
                if (w_idx == 2) {
                    vt[((size_t)(b * 16 + h) * 64 + hd) * 512 + l] = f2b(x);
                } else {
                    float partner = __shfl_xor(x, 1);
                    float s = sin_enc[(size_t)l * 1024 + (n & ~1)];
                    float c = sin_enc[(size_t)l * 1024 + (n | 1)];
                    float y = (n & 1) ? (x * c + partner * s) : (x * c - partner * s);
                    if (w_idx == 0) y *= 0.125f;
                    u16* dst = (w_idx == 0) ? qh : kh;
                    dst[((size_t)(b * 16 + h) * 512 + l) * 64 + hd] = f2b(y);
                }
            }
        }
    }
}

// ---------------------------------------------------------------------------
// Kernel 1 (fallback, ws < 64 MiB): f32 staging path (round-3, verified).
// ---------------------------------------------------------------------------
__global__ __launch_bounds__(256) void gemm_proj_f32(
    const float* __restrict__ qin, const float* __restrict__ kin, const float* __restrict__ vin,
    const float* __restrict__ Wq, const float* __restrict__ bq,
    const float* __restrict__ Wk, const float* __restrict__ bk,
    const float* __restrict__ Wv, const float* __restrict__ bv,
    const float* __restrict__ sin_enc,
    u16* __restrict__ qh, u16* __restrict__ kh, u16* __restrict__ vt)
{
    __shared__ __align__(16) u16 lA[128 * 32];
    __shared__ __align__(16) u16 lB[128 * 32];
    const int t = threadIdx.x, wave = t >> 6, lane = t & 63;
    const int bx = blockIdx.x;
    const int w_idx = bx >> 3;
    const int n0 = (bx & 7) << 7;
    const int m0 = blockIdx.y << 7;
    const float* A    = (w_idx == 0) ? qin : (w_idx == 1 ? kin : vin);
    const float* W    = (w_idx == 0) ? Wq  : (w_idx == 1 ? Wk  : Wv);
    const float* bias = (w_idx == 0) ? bq  : (w_idx == 1 ? bk  : bv);

    const int wr = wave >> 1, wc = wave & 1;
    const int col16 = lane & 15, g16 = lane >> 4;
    f32x4 acc[4][4] = {};

    const int c0   = wave * 128 + lane;
    const int row0 = c0 >> 2;
    const int kp   = (c0 & 3) << 3;
    const size_t gA0 = (size_t)(m0 + row0) * 1024 + kp;
    const size_t gB0 = (size_t)(n0 + row0) * 1024 + kp;
    u16* wA0 = lA + c0 * 8;
    u16* wA1 = lA + (c0 + 64) * 8;
    u16* wB0 = lB + c0 * 8;
    u16* wB1 = lB + (c0 + 64) * 8;

    bf16x8 ra0 = ld8f(A + gA0);
    bf16x8 ra1 = ld8f(A + gA0 + 16 * 1024);
    bf16x8 rb0 = ld8f(W + gB0);
    bf16x8 rb1 = ld8f(W + gB0 + 16 * 1024);

    for (int kk = 32; kk <= 1024; kk += 32) {
        __syncthreads();
        *(bf16x8*)wA0 = ra0; *(bf16x8*)wA1 = ra1;
        *(bf16x8*)wB0 = rb0; *(bf16x8*)wB1 = rb1;
        __syncthreads();
        if (kk < 1024) {
            ra0 = ld8f(A + gA0 + kk);
            ra1 = ld8f(A + gA0 + kk + 16 * 1024);
            rb0 = ld8f(W + gB0 + kk);
            rb1 = ld8f(W + gB0 + kk + 16 * 1024);
        }
        const u16* pA = lA + (wr * 64 + col16) * 32 + g16 * 8;
        const u16* pB = lB + (wc * 64 + col16) * 32 + g16 * 8;
        bf16x8 af[4], bfr[4];
#pragma unroll
        for (int i = 0; i < 4; i++) {
            af[i]  = *(const bf16x8*)(pA + i * 512);
            bfr[i] = *(const bf16x8*)(pB + i * 512);
        }
#pragma unroll
        for (int mi = 0; mi < 4; mi++)
#pragma unroll
            for (int ni = 0; ni < 4; ni++)
                acc[mi][ni] = MFMA16(af[mi], bfr[ni], acc[mi][ni]);
    }

#pragma unroll
    for (int ni = 0; ni < 4; ni++) {
        const int n = n0 + wc * 64 + ni * 16 + col16;
        const float bn = bias[n];
        const int h = n >> 6, hd = n & 63;
#pragma unroll
        for (int mi = 0; mi < 4; mi++) {
#pragma unroll
            for (int r = 0; r < 4; r++) {
                const int m = m0 + wr * 64 + mi * 16 + g16 * 4 + r;
                const int b = m >> 9, l = m & 511;
                float x = acc[mi][ni][r] + bn;
                if (w_idx == 2) {
                    vt[((size_t)(b * 16 + h) * 64 + hd) * 512 + l] = f2b(x);
                } else {
                    float partner = __shfl_xor(x, 1);
                    float s = sin_enc[(size_t)l * 1024 + (n & ~1)];
                    float c = sin_enc[(size_t)l * 1024 + (n | 1)];
                    float y = (n & 1) ? (x * c + partner * s) : (x * c - partner * s);
                    if (w_idx == 0) y *= 0.125f;
                    u16* dst = (w_idx == 0) ? qh : kh;
                    dst[((size_t)(b * 16 + h) * 512 + l) * 64 + hd] = f2b(y);
                }
            }
        }
    }
}

// ---------------------------------------------------------------------------
// Kernel 2: flash attention with dist bias + key mask.
// Grid 1024, 256 thr. dist staged via coalesced int4 -> u8 LDS tile.
// (blocks sharing a dist tile are stride-8 apart -> same XCD already)
// ---------------------------------------------------------------------------
__global__ __launch_bounds__(256) void attn_kernel(
    const u16* __restrict__ qh, const u16* __restrict__ kh, const u16* __restrict__ vt,
    const float* __restrict__ demb_g, const int* __restrict__ length,
    const int* __restrict__ dist, u16* __restrict__ ctx)
{
    __shared__ __align__(16) u16 Qs[64 * 64];
    __shared__ __align__(16) u16 Ks[64 * 64];
    __shared__ __align__(16) u16 Vs[64 * 64];
    __shared__ __align__(16) u16 Ps[4][16 * 64];
    __shared__ __align__(16) uint8_t Ds[64 * 64];
    __shared__ float demb[64];

    const int t = threadIdx.x, wave = t >> 6, lane = t & 63;
    const int bxx = blockIdx.x;
    const int qt = bxx & 7, bh = bxx >> 3;
    const int b = bh >> 4, h = bh & 15;
    if (t < 64) demb[t] = demb_g[t * 16 + h];
    const int len_b = length[b];
    const int ktmax = (len_b + 63) >> 6;
    const int col16 = lane & 15, g16 = lane >> 4;
    const int c0 = wave * 128 + lane, c1 = c0 + 64;

    const u16* qbase = qh + (size_t)(bh * 512 + qt * 64) * 64;
    {
        uint4 rq0 = *(const uint4*)(qbase + c0 * 8);
        uint4 rq1 = *(const uint4*)(qbase + c1 * 8);
        *(uint4*)((char*)Qs + c0 * 16) = rq0;
        *(uint4*)((char*)Qs + c1 * 16) = rq1;
    }

    const u16* kbase = kh + (size_t)bh * 512 * 64;
    const u16* vbase = vt + (size_t)bh * 64 * 512;
    const int qrow_base = qt * 64 + wave * 16 + g16 * 4;

    const int drow = t >> 2;
    const int dcol = (t & 3) << 4;
    const int* dg = dist + (size_t)b * 512 * 512 + (size_t)(qt * 64 + drow) * 512 + dcol;
    uint32_t* DsW = (uint32_t*)(Ds + drow * 64 + dcol);

    uint4 rk0 = *(const uint4*)(kbase + c0 * 8);
    uint4 rk1 = *(const uint4*)(kbase + c1 * 8);
    uint4 rv0 = *(const uint4*)(vbase + (size_t)(c0 >> 3) * 512 + (c0 & 7) * 8);
    uint4 rv1 = *(const uint4*)(vbase + (size_t)(c1 >> 3) * 512 + (c1 & 7) * 8);
    int4 dd[4];
#pragma unroll
    for (int j = 0; j < 4; j++) dd[j] = *(const int4*)(dg + j * 4);

    __syncthreads();
    const u16* pQ = Qs + (wave * 16 + col16) * 64 + g16 * 8;
    const bf16x8 qa0 = *(const bf16x8*)pQ;
    const bf16x8 qa1 = *(const bf16x8*)(pQ + 32);

    f32x4 oacc[4] = {};
    float mrow[4], lrow[4];
#pragma unroll
    for (int r = 0; r < 4; r++) { mrow[r] = -1e30f; lrow[r] = 0.f; }

    for (int kt = 0; kt < ktmax; kt++) {
        __syncthreads();
        *(uint4*)((char*)Ks + c0 * 16) = rk0;
        *(uint4*)((char*)Ks + c1 * 16) = rk1;
        *(uint4*)((char*)Vs + c0 * 16) = rv0;
        *(uint4*)((char*)Vs + c1 * 16) = rv1;
#pragma unroll
        for (int j = 0; j < 4; j++)
            DsW[j] = (uint32_t)(dd[j].x & 63) | ((uint32_t)(dd[j].y & 63) << 8) |
                     ((uint32_t)(dd[j].z & 63) << 16) | ((uint32_t)(dd[j].w & 63) << 24);
        __syncthreads();
        if (kt + 1 < ktmax) {
            const u16* kb = kbase + (size_t)(kt + 1) * 64 * 64;
            rk0 = *(const uint4*)(kb + c0 * 8);
            rk1 = *(const uint4*)(kb + c1 * 8);
            rv0 = *(const uint4*)(vbase + (size_t)(c0 >> 3) * 512 + (kt + 1) * 64 + (c0 & 7) * 8);
            rv1 = *(const uint4*)(vbase + (size_t)(c1 >> 3) * 512 + (kt + 1) * 64 + (c1 & 7) * 8);
            const int* dgn = dg + (kt + 1) * 64;
#pragma unroll
            for (int j = 0; j < 4; j++) dd[j] = *(const int4*)(dgn + j * 4);
        }

        f32x4 sacc[4] = {};
#pragma unroll
        for (int ni = 0; ni < 4; ni++) {
            const u16* pK = Ks + (ni * 16 + col16) * 64 + g16 * 8;
            bf16x8 kf0 = *(const bf16x8*)pK;
            bf16x8 kf1 = *(const bf16x8*)(pK + 32);
            sacc[ni] = MFMA16(qa0, kf0, sacc[ni]);
            sacc[ni] = MFMA16(qa1, kf1, sacc[ni]);
        }

        float rmax[4] = {-1e30f, -1e30f, -1e30f, -1e30f};
        const int qrl = wave * 16 + g16 * 4;
#pragma unroll
        for (int ni = 0; ni < 4; ni++) {
            const int kcl = ni * 16 + col16;
            const bool masked = (kt * 64 + kcl) >= len_b;
#pragma unroll
            for (int r = 0; r < 4; r++) {
                float s = sacc[ni][r] + demb[Ds[(qrl + r) * 64 + kcl]];
                s = masked ? -1e9f : s;
                sacc[ni][r] = s;
                rmax[r] = fmaxf(rmax[r], s);
            }
        }
#pragma unroll
        for (int off = 1; off < 16; off <<= 1)
#pragma unroll
            for (int r = 0; r < 4; r++) rmax[r] = fmaxf(rmax[r], __shfl_xor(rmax[r], off));

        float alpha[4], rsum[4];
#pragma unroll
        for (int r = 0; r < 4; r++) {
            float mn = fmaxf(mrow[r], rmax[r]);
            alpha[r] = __expf(mrow[r] - mn);
            mrow[r] = mn;
            rsum[r] = 0.f;
        }
#pragma unroll
        for (int ni = 0; ni < 4; ni++)
#pragma unroll
            for (int r = 0; r < 4; r++) {
                float p = __expf(sacc[ni][r] - mrow[r]);
                sacc[ni][r] = p;
                rsum[r] += p;
            }
#pragma unroll
        for (int off = 1; off < 16; off <<= 1)
#pragma unroll
            for (int r = 0; r < 4; r++) rsum[r] += __shfl_xor(rsum[r], off);
#pragma unroll
        for (int r = 0; r < 4; r++) lrow[r] = lrow[r] * alpha[r] + rsum[r];
#pragma unroll
        for (int di = 0; di < 4; di++)
#pragma unroll
            for (int r = 0; r < 4; r++) oacc[di][r] *= alpha[r];

        u16* Pw = &Ps[wave][0];
#pragma unroll
        for (int ni = 0; ni < 4; ni++)
#pragma unroll
            for (int r = 0; r < 4; r++)
                Pw[(g16 * 4 + r) * 64 + ni * 16 + col16] = f2b(sacc[ni][r]);
        __syncthreads();

        const u16* pP = Pw + col16 * 64 + g16 * 8;
        bf16x8 pa0 = *(const bf16x8*)pP;
        bf16x8 pa1 = *(const bf16x8*)(pP + 32);
#pragma unroll
        for (int di = 0; di < 4; di++) {
            const u16* pV = Vs + (di * 16 + col16) * 64 + g16 * 8;
            bf16x8 vf0 = *(const bf16x8*)pV;
            bf16x8 vf1 = *(const bf16x8*)(pV + 32);
            oacc[di] = MFMA16(pa0, vf0, oacc[di]);
            oacc[di] = MFMA16(pa1, vf1, oacc[di]);
        }
    }

#pragma unroll
    for (int di = 0; di < 4; di++)
#pragma unroll
        for (int r = 0; r < 4; r++) {
            const int qrow = qrow_base + r;
            const int d = di * 16 + col16;
            const float inv_l = 1.0f / fmaxf(lrow[r], 1e-30f);
            ctx[(size_t)(b * 512 + qrow) * 1024 + h * 64 + d] = f2b(oacc[di][r] * inv_l);
        }
}

// ---------------------------------------------------------------------------
// Kernel 3: ctx(bf16) @ Wo^T(bf16) + bo -> f32. 64x64 tiles.
// Grid (64, 16): x = m-tile, y = n-tile; linear = x + y*64, 64 % 8 == 0 ->
// the 16 n-tiles sharing a ctx m-tile land on the same XCD (L2 reuse).
// ---------------------------------------------------------------------------
__global__ __launch_bounds__(256, 4) void gemm_out_b(
    const u16* __restrict__ ctx, const u16* __restrict__ wob,
    const float* __restrict__ bo, float* __restrict__ out)
{
    __shared__ __align__(16) u16 lA[2][64 * 32];
    __shared__ __align__(16) u16 lB[2][64 * 32];
    const int t = threadIdx.x, wave = t >> 6, lane = t & 63;
    const int m0 = blockIdx.x << 6;
    const int n0 = blockIdx.y << 6;
    const int wr = wave >> 1, wc = wave & 1;
    const int col16 = lane & 15, g16 = lane >> 4;
    f32x4 acc[2][2] = {};

    // 256 chunks per tile, 1/thread: wave w covers chunks w*64+lane
    const int cA = wave * 64 + lane;
    const u16* gA = ctx + (size_t)(m0 + (cA >> 2)) * 1024 + ((cA & 3) << 3);
    const u16* gB = wob + (size_t)(n0 + (cA >> 2)) * 1024 + ((cA & 3) << 3);

    load16(gA, (char*)lA[0] + wave * 1024);
    load16(gB, (char*)lB[0] + wave * 1024);

    for (int it = 0; it < 32; ++it) {
        const int buf = it & 1, nbuf = buf ^ 1;
        __syncthreads();
        if (it + 1 < 32) {
            const int kk = (it + 1) << 5;
            load16(gA + kk, (char*)lA[nbuf] + wave * 1024);
            load16(gB + kk, (char*)lB[nbuf] + wave * 1024);
        }
        const u16* pA = lA[buf] + (wr * 32 + col16) * 32 + g16 * 8;
        const u16* pB = lB[buf] + (wc * 32 + col16) * 32 + g16 * 8;
        bf16x8 af[2], bfr[2];
#pragma unroll
        for (int i = 0; i < 2; i++) {
            af[i]  = *(const bf16x8*)(pA + i * 512);
            bfr[i] = *(const bf16x8*)(pB + i * 512);
        }
#pragma unroll
        for (int mi = 0; mi < 2; mi++)
#pragma unroll
            for (int ni = 0; ni < 2; ni++)
                acc[mi][ni] = MFMA16(af[mi], bfr[ni], acc[mi][ni]);
    }

#pragma unroll
    for (int ni = 0; ni < 2; ni++) {
        const int n = n0 + wc * 32 + ni * 16 + col16;
        const float bn = bo[n];
#pragma unroll
        for (int mi = 0; mi < 2; mi++)
#pragma unroll
            for (int r = 0; r < 4; r++) {
                const int m = m0 + wr * 32 + mi * 16 + g16 * 4 + r;
                out[(size_t)m * 1024 + n] = acc[mi][ni][r] + bn;
            }
    }
}

// ---------------------------------------------------------------------------
// Kernel 3 (fallback): ctx(bf16) @ Wo^T(f32) + bo -> f32 (round-3 path).
// ---------------------------------------------------------------------------
__global__ __launch_bounds__(256) void gemm_out_f32(
    const u16* __restrict__ ctx, const float* __restrict__ Wo,
    const float* __restrict__ bo, float* __restrict__ out)
{
    __shared__ __align__(16) u16 lA[128 * 32];
    __shared__ __align__(16) u16 lB[128 * 32];
    const int t = threadIdx.x, wave = t >> 6, lane = t & 63;
    const int n0 = blockIdx.x << 7;
    const int m0 = blockIdx.y << 7;
    const int wr = wave >> 1, wc = wave & 1;
    const int col16 = lane & 15, g16 = lane >> 4;
    f32x4 acc[4][4] = {};

    const int c0   = wave * 128 + lane;
    const int row0 = c0 >> 2;
    const int kp   = (c0 & 3) << 3;
    const u16* gA = ctx + (size_t)(m0 + row0) * 1024 + kp;
    const size_t gB0 = (size_t)(n0 + row0) * 1024 + kp;
    u16* wA0 = lA + c0 * 8;
    u16* wA1 = lA + (c0 + 64) * 8;
    u16* wB0 = lB + c0 * 8;
    u16* wB1 = lB + (c0 + 64) * 8;

    uint4 ua0 = *(const uint4*)gA;
    uint4 ua1 = *(const uint4*)(gA + 16 * 1024);
    bf16x8 ra0 = *(bf16x8*)&ua0, ra1 = *(bf16x8*)&ua1;
    bf16x8 rb0 = ld8f(Wo + gB0);
    bf16x8 rb1 = ld8f(Wo + gB0 + 16 * 1024);

    for (int kk = 32; kk <= 1024; kk += 32) {
        __syncthreads();
        *(bf16x8*)wA0 = ra0; *(bf16x8*)wA1 = ra1;
        *(bf16x8*)wB0 = rb0; *(bf16x8*)wB1 = rb1;
        __syncthreads();
        if (kk < 1024) {
            uint4 t0 = *(const uint4*)(gA + kk);
            uint4 t1 = *(const uint4*)(gA + kk + 16 * 1024);
            ra0 = *(bf16x8*)&t0; ra1 = *(bf16x8*)&t1;
            rb0 = ld8f(Wo + gB0 + kk);
            rb1 = ld8f(Wo + gB0 + kk + 16 * 1024);
        }
        const u16* pA = lA + (wr * 64 + col16) * 32 + g16 * 8;
        const u16* pB = lB + (wc * 64 + col16) * 32 + g16 * 8;
        bf16x8 af[4], bfr[4];
#pragma unroll
        for (int i = 0; i < 4; i++) {
            af[i]  = *(const bf16x8*)(pA + i * 512);
            bfr[i] = *(const bf16x8*)(pB + i * 512);
        }
#pragma unroll
        for (int mi = 0; mi < 4; mi++)
#pragma unroll
            for (int ni = 0; ni < 4; ni++)
                acc[mi][ni] = MFMA16(af[mi], bfr[ni], acc[mi][ni]);
    }

#pragma unroll
    for (int ni = 0; ni < 4; ni++) {
        const int n = n0 + wc * 64 + ni * 16 + col16;
        const float bn = bo[n];
#pragma unroll
        for (int mi = 0; mi < 4; mi++)
#pragma unroll
            for (int r = 0; r < 4; r++) {
                const int m = m0 + wr * 64 + mi * 16 + g16 * 4 + r;
                out[(size_t)m * 1024 + n] = acc[mi][ni][r] + bn;
            }
    }
}

extern "C" void kernel_launch(void* const* d_in, const int* in_sizes, int n_in,
                              void* d_out, int out_size, void* d_ws, size_t ws_size,
                              hipStream_t stream) {
    const float* q       = (const float*)d_in[0];
    const float* k       = (const float*)d_in[1];
    const float* v       = (const float*)d_in[2];
    const float* Wq      = (const float*)d_in[3];
    const float* bq      = (const float*)d_in[4];
    const float* Wk      = (const float*)d_in[5];
    const float* bk      = (const float*)d_in[6];
    const float* Wv      = (const float*)d_in[7];
    const float* bv      = (const float*)d_in[8];
    const float* Wo      = (const float*)d_in[9];
    const float* bo      = (const float*)d_in[10];
    const float* demb    = (const float*)d_in[11];
    const float* sin_enc = (const float*)d_in[12];
    const int* length    = (const int*)d_in[13];
    const int* dist      = (const int*)d_in[14];

    const size_t SLOT = 4194304;          // 8 MiB region, in u16 elements
    u16* qh  = (u16*)d_ws;
    u16* kh  = qh + SLOT;
    u16* vt  = kh + SLOT;
    u16* ctx = vt + SLOT;

    if (ws_size >= (size_t)64 * 1024 * 1024) {
        u16* wqb = ctx + SLOT;            // 4 x 2 MiB weight regions
        u16* wkb = wqb + 1048576;
        u16* wvb = wkb + 1048576;
        u16* wob = wvb + 1048576;
        convert_k<<<dim3(512, 4), 256, 0, stream>>>(Wq, Wk, Wv, Wo, wqb, wkb, wvb, wob);
        gemm_proj_b<<<dim3(192, 8), 256, 0, stream>>>(q, k, v, wqb, wkb, wvb,
                                                      bq, bk, bv, sin_enc, qh, kh, vt);
        attn_kernel<<<dim3(1024), 256, 0, stream>>>(qh, kh, vt, demb, length, dist, ctx);
        gemm_out_b<<<dim3(64, 16), 256, 0, stream>>>(ctx, wob, bo, (float*)d_out);
    } else {
        gemm_proj_f32<<<dim3(24, 32), 256, 0, stream>>>(q, k, v, Wq, bq, Wk, bk, Wv, bv,
                                                        sin_enc, qh, kh, vt);
        attn_kernel<<<dim3(1024), 256, 0, stream>>>(qh, kh, vt, demb, length, dist, ctx);
        gemm_out_f32<<<dim3(8, 32), 256, 0, stream>>>(ctx, Wo, bo, (float*)d_out);
    }
}

// Round 8
// 254.450 us; speedup vs baseline: 1.0785x; 1.0511x over previous
//
#include <hip/hip_runtime.h>
#include <stdint.h>

typedef unsigned short u16;
typedef __bf16 bf16x8 __attribute__((ext_vector_type(8)));
typedef float f32x4 __attribute__((ext_vector_type(4)));

#define MFMA16(a, b, c) __builtin_amdgcn_mfma_f32_16x16x32_bf16(a, b, c, 0, 0, 0)

__device__ __forceinline__ float b2f(u16 u) { return __uint_as_float(((uint32_t)u) << 16); }
__device__ __forceinline__ u16 f2b(float f) {
    uint32_t x = __float_as_uint(f);
    return (u16)((x + 0x7fffu + ((x >> 16) & 1u)) >> 16);
}
// async global->LDS, 16B per lane; lds dest = wave-uniform base + lane*16
__device__ __forceinline__ void load16(const void* g, void* l) {
    __builtin_amdgcn_global_load_lds(
        (const __attribute__((address_space(1))) uint32_t*)(uintptr_t)g,
        (__attribute__((address_space(3))) uint32_t*)(uint32_t)(uintptr_t)l,
        16, 0, 0);
}
// 8 consecutive f32 -> bf16x8
__device__ __forceinline__ bf16x8 ld8f(const float* f) {
    float4 a = *(const float4*)f;
    float4 b = *(const float4*)(f + 4);
    bf16x8 o;
    o[0] = (__bf16)a.x; o[1] = (__bf16)a.y; o[2] = (__bf16)a.z; o[3] = (__bf16)a.w;
    o[4] = (__bf16)b.x; o[5] = (__bf16)b.y; o[6] = (__bf16)b.z; o[7] = (__bf16)b.w;
    return o;
}

// ---------------------------------------------------------------------------
// Kernel 0: f32 -> bf16 conversion of q,k,v,Wq,Wk,Wv,Wo. grid (2048, 7).
// ---------------------------------------------------------------------------
__global__ __launch_bounds__(256) void convert_k(
    const float* __restrict__ q, const float* __restrict__ k, const float* __restrict__ v,
    const float* __restrict__ Wq, const float* __restrict__ Wk,
    const float* __restrict__ Wv, const float* __restrict__ Wo,
    u16* __restrict__ qb, u16* __restrict__ kb, u16* __restrict__ vb,
    u16* __restrict__ wqb, u16* __restrict__ wkb, u16* __restrict__ wvb,
    u16* __restrict__ wob)
{
    const float* src; u16* dst; int n8;
    switch (blockIdx.y) {
        case 0: src = q;  dst = qb;  n8 = 524288; break;
        case 1: src = k;  dst = kb;  n8 = 524288; break;
        case 2: src = v;  dst = vb;  n8 = 524288; break;
        case 3: src = Wq; dst = wqb; n8 = 131072; break;
        case 4: src = Wk; dst = wkb; n8 = 131072; break;
        case 5: src = Wv; dst = wvb; n8 = 131072; break;
        default: src = Wo; dst = wob; n8 = 131072; break;
    }
    int i = blockIdx.x * 256 + threadIdx.x;
    if (i >= n8) return;
    bf16x8 o = ld8f(src + (size_t)i * 8);
    *(bf16x8*)(dst + (size_t)i * 8) = o;
}

// ---------------------------------------------------------------------------
// Kernel 1: bf16 QKV projection + bias + RoPE + head split.
// 64x128 tiles. Grid (192, 8): x = (w_idx, m-tile) group, y = n-tile.
// Linear id = x + y*192, 192 % 8 == 0 -> all 8 n-tiles of a group land on the
// same XCD: the bf16 A-tile (128 KB) is fetched once, L2-hit 7 times.
// All staging via global_load_lds; single barrier per K-tile; LDS dbuf.
// ---------------------------------------------------------------------------
__global__ __launch_bounds__(256, 6) void gemm_proj_b(
    const u16* __restrict__ qb, const u16* __restrict__ kb, const u16* __restrict__ vb,
    const u16* __restrict__ wqb, const u16* __restrict__ wkb, const u16* __restrict__ wvb,
    const float* __restrict__ bq, const float* __restrict__ bk, const float* __restrict__ bv,
    const float* __restrict__ sin_enc,
    u16* __restrict__ qh, u16* __restrict__ kh, u16* __restrict__ vt)
{
    __shared__ __align__(16) u16 lA[2][64 * 32];    // 4 KB each
    __shared__ __align__(16) u16 lB[2][128 * 32];   // 8 KB each
    const int t = threadIdx.x, wave = t >> 6, lane = t & 63;
    const int group = blockIdx.x;          // 0..191
    const int w_idx = group >> 6;          // 0..2 (Q/K/V)
    const int m0 = (group & 63) << 6;      // m-tile
    const int n0 = blockIdx.y << 7;        // n-tile
    const u16* A = (w_idx == 0) ? qb : (w_idx == 1 ? kb : vb);
    const u16* W = (w_idx == 0) ? wqb : (w_idx == 1 ? wkb : wvb);
    const float* bias = (w_idx == 0) ? bq : (w_idx == 1 ? bk : bv);

    const int wr = wave >> 1, wc = wave & 1;        // 2x2 wave quadrants
    const int col16 = lane & 15, g16 = lane >> 4;
    f32x4 acc[2][4] = {};

    // A: 64x32 tile = 256 x 16B chunks, 1/thread. chunk c: row c>>2, kph (c&3)*8
    const int cA = wave * 64 + lane;
    const u16* gA = A + (size_t)(m0 + (cA >> 2)) * 1024 + ((cA & 3) << 3);
    // B: 128x32 tile = 512 chunks, 2/thread (c0, c0+64)
    const int c0 = wave * 128 + lane;
    const u16* gB = W + (size_t)(n0 + (c0 >> 2)) * 1024 + ((c0 & 3) << 3);

    // preload tile 0 into buf0
    load16(gA, (char*)lA[0] + wave * 1024);
    load16(gB, (char*)lB[0] + wave * 2048);
    load16(gB + 16 * 1024, (char*)lB[0] + wave * 2048 + 1024);

    for (int it = 0; it < 32; ++it) {
        const int buf = it & 1, nbuf = buf ^ 1;
        __syncthreads();    // tile-it staging drained & visible
        if (it + 1 < 32) {  // stage tile it+1 into nbuf; stays in flight over MFMA
            const int kk = (it + 1) << 5;
            load16(gA + kk, (char*)lA[nbuf] + wave * 1024);
            load16(gB + kk, (char*)lB[nbuf] + wave * 2048);
            load16(gB + kk + 16 * 1024, (char*)lB[nbuf] + wave * 2048 + 1024);
        }
        const u16* pA = lA[buf] + (wr * 32 + col16) * 32 + g16 * 8;
        const u16* pB = lB[buf] + (wc * 64 + col16) * 32 + g16 * 8;
        bf16x8 af[2], bfr[4];
#pragma unroll
        for (int i = 0; i < 2; i++) af[i] = *(const bf16x8*)(pA + i * 512);
#pragma unroll
        for (int i = 0; i < 4; i++) bfr[i] = *(const bf16x8*)(pB + i * 512);
#pragma unroll
        for (int mi = 0; mi < 2; mi++)
#pragma unroll
            for (int ni = 0; ni < 4; ni++)
                acc[mi][ni] = MFMA16(af[mi], bfr[ni], acc[mi][ni]);
    }

    // epilogue: bias + rope(+scale for Q) + head-split store
#pragma unroll
    for (int ni = 0; ni < 4; ni++) {
        const int n = n0 + wc * 64 + ni * 16 + col16;
        const float bn = bias[n];
        const int h = n >> 6, hd = n & 63;
#pragma unroll
        for (int mi = 0; mi < 2; mi++) {
#pragma unroll
            for (int r = 0; r < 4; r++) {
                const int m = m0 + wr * 32 + mi * 16 + g16 * 4 + r;
                const int b = m >> 9, l = m & 511;
                float x = acc[mi][ni][r] + bn;
                if (w_idx == 2) {
                    vt[((size_t)(b * 16 + h) * 64 + hd) * 512 + l] = f2b(x);
                } else {
                    float partner = __shfl_xor(x, 1);
                    float s = sin_enc[(size_t)l * 1024 + (n & ~1)];
                    float c = sin_enc[(size_t)l * 1024 + (n | 1)];
                    float y = (n & 1) ? (x * c + partner * s) : (x * c - partner * s);
                    if (w_idx == 0) y *= 0.125f;
                    u16* dst = (w_idx == 0) ? qh : kh;
                    dst[((size_t)(b * 16 + h) * 512 + l) * 64 + hd] = f2b(y);
                }
            }
        }
    }
}

// ---------------------------------------------------------------------------
// Kernel 1 (fallback, ws < 64 MiB): f32 staging path (round-3, verified).
// ---------------------------------------------------------------------------
__global__ __launch_bounds__(256) void gemm_proj_f32(
    const float* __restrict__ qin, const float* __restrict__ kin, const float* __restrict__ vin,
    const float* __restrict__ Wq, const float* __restrict__ bq,
    const float* __restrict__ Wk, const float* __restrict__ bk,
    const float* __restrict__ Wv, const float* __restrict__ bv,
    const float* __restrict__ sin_enc,
    u16* __restrict__ qh, u16* __restrict__ kh, u16* __restrict__ vt)
{
    __shared__ __align__(16) u16 lA[128 * 32];
    __shared__ __align__(16) u16 lB[128 * 32];
    const int t = threadIdx.x, wave = t >> 6, lane = t & 63;
    const int bx = blockIdx.x;
    const int w_idx = bx >> 3;
    const int n0 = (bx & 7) << 7;
    const int m0 = blockIdx.y << 7;
    const float* A    = (w_idx == 0) ? qin : (w_idx == 1 ? kin : vin);
    const float* W    = (w_idx == 0) ? Wq  : (w_idx == 1 ? Wk  : Wv);
    const float* bias = (w_idx == 0) ? bq  : (w_idx == 1 ? bk  : bv);

    const int wr = wave >> 1, wc = wave & 1;
    const int col16 = lane & 15, g16 = lane >> 4;
    f32x4 acc[4][4] = {};

    const int c0   = wave * 128 + lane;
    const int row0 = c0 >> 2;
    const int kp   = (c0 & 3) << 3;
    const size_t gA0 = (size_t)(m0 + row0) * 1024 + kp;
    const size_t gB0 = (size_t)(n0 + row0) * 1024 + kp;
    u16* wA0 = lA + c0 * 8;
    u16* wA1 = lA + (c0 + 64) * 8;
    u16* wB0 = lB + c0 * 8;
    u16* wB1 = lB + (c0 + 64) * 8;

    bf16x8 ra0 = ld8f(A + gA0);
    bf16x8 ra1 = ld8f(A + gA0 + 16 * 1024);
    bf16x8 rb0 = ld8f(W + gB0);
    bf16x8 rb1 = ld8f(W + gB0 + 16 * 1024);

    for (int kk = 32; kk <= 1024; kk += 32) {
        __syncthreads();
        *(bf16x8*)wA0 = ra0; *(bf16x8*)wA1 = ra1;
        *(bf16x8*)wB0 = rb0; *(bf16x8*)wB1 = rb1;
        __syncthreads();
        if (kk < 1024) {
            ra0 = ld8f(A + gA0 + kk);
            ra1 = ld8f(A + gA0 + kk + 16 * 1024);
            rb0 = ld8f(W + gB0 + kk);
            rb1 = ld8f(W + gB0 + kk + 16 * 1024);
        }
        const u16* pA = lA + (wr * 64 + col16) * 32 + g16 * 8;
        const u16* pB = lB + (wc * 64 + col16) * 32 + g16 * 8;
        bf16x8 af[4], bfr[4];
#pragma unroll
        for (int i = 0; i < 4; i++) {
            af[i]  = *(const bf16x8*)(pA + i * 512);
            bfr[i] = *(const bf16x8*)(pB + i * 512);
        }
#pragma unroll
        for (int mi = 0; mi < 4; mi++)
#pragma unroll
            for (int ni = 0; ni < 4; ni++)
                acc[mi][ni] = MFMA16(af[mi], bfr[ni], acc[mi][ni]);
    }

#pragma unroll
    for (int ni = 0; ni < 4; ni++) {
        const int n = n0 + wc * 64 + ni * 16 + col16;
        const float bn = bias[n];
        const int h = n >> 6, hd = n & 63;
#pragma unroll
        for (int mi = 0; mi < 4; mi++) {
#pragma unroll
            for (int r = 0; r < 4; r++) {
                const int m = m0 + wr * 64 + mi * 16 + g16 * 4 + r;
                const int b = m >> 9, l = m & 511;
                float x = acc[mi][ni][r] + bn;
                if (w_idx == 2) {
                    vt[((size_t)(b * 16 + h) * 64 + hd) * 512 + l] = f2b(x);
                } else {
                    float partner = __shfl_xor(x, 1);
                    float s = sin_enc[(size_t)l * 1024 + (n & ~1)];
                    float c = sin_enc[(size_t)l * 1024 + (n | 1)];
                    float y = (n & 1) ? (x * c + partner * s) : (x * c - partner * s);
                    if (w_idx == 0) y *= 0.125f;
                    u16* dst = (w_idx == 0) ? qh : kh;
                    dst[((size_t)(b * 16 + h) * 512 + l) * 64 + hd] = f2b(y);
                }
            }
        }
    }
}

// ---------------------------------------------------------------------------
// Kernel 2: flash attention with dist bias + key mask.
// Grid 1024, 256 thr. 2 barriers per KV tile (P round-trip is wave-private;
// its ds_write->ds_read ordering is handled by compiler lgkmcnt, no barrier).
// ---------------------------------------------------------------------------
__global__ __launch_bounds__(256) void attn_kernel(
    const u16* __restrict__ qh, const u16* __restrict__ kh, const u16* __restrict__ vt,
    const float* __restrict__ demb_g, const int* __restrict__ length,
    const int* __restrict__ dist, u16* __restrict__ ctx)
{
    __shared__ __align__(16) u16 Qs[64 * 64];
    __shared__ __align__(16) u16 Ks[64 * 64];
    __shared__ __align__(16) u16 Vs[64 * 64];
    __shared__ __align__(16) u16 Ps[4][16 * 64];
    __shared__ __align__(16) uint8_t Ds[64 * 64];
    __shared__ float demb[64];

    const int t = threadIdx.x, wave = t >> 6, lane = t & 63;
    const int bxx = blockIdx.x;
    const int qt = bxx & 7, bh = bxx >> 3;
    const int b = bh >> 4, h = bh & 15;
    if (t < 64) demb[t] = demb_g[t * 16 + h];
    const int len_b = length[b];
    const int ktmax = (len_b + 63) >> 6;
    const int col16 = lane & 15, g16 = lane >> 4;
    const int c0 = wave * 128 + lane, c1 = c0 + 64;

    const u16* qbase = qh + (size_t)(bh * 512 + qt * 64) * 64;
    {
        uint4 rq0 = *(const uint4*)(qbase + c0 * 8);
        uint4 rq1 = *(const uint4*)(qbase + c1 * 8);
        *(uint4*)((char*)Qs + c0 * 16) = rq0;
        *(uint4*)((char*)Qs + c1 * 16) = rq1;
    }

    const u16* kbase = kh + (size_t)bh * 512 * 64;
    const u16* vbase = vt + (size_t)bh * 64 * 512;
    const int qrow_base = qt * 64 + wave * 16 + g16 * 4;

    const int drow = t >> 2;
    const int dcol = (t & 3) << 4;
    const int* dg = dist + (size_t)b * 512 * 512 + (size_t)(qt * 64 + drow) * 512 + dcol;
    uint32_t* DsW = (uint32_t*)(Ds + drow * 64 + dcol);

    uint4 rk0 = *(const uint4*)(kbase + c0 * 8);
    uint4 rk1 = *(const uint4*)(kbase + c1 * 8);
    uint4 rv0 = *(const uint4*)(vbase + (size_t)(c0 >> 3) * 512 + (c0 & 7) * 8);
    uint4 rv1 = *(const uint4*)(vbase + (size_t)(c1 >> 3) * 512 + (c1 & 7) * 8);
    int4 dd[4];
#pragma unroll
    for (int j = 0; j < 4; j++) dd[j] = *(const int4*)(dg + j * 4);

    __syncthreads();
    const u16* pQ = Qs + (wave * 16 + col16) * 64 + g16 * 8;
    const bf16x8 qa0 = *(const bf16x8*)pQ;
    const bf16x8 qa1 = *(const bf16x8*)(pQ + 32);

    f32x4 oacc[4] = {};
    float mrow[4], lrow[4];
#pragma unroll
    for (int r = 0; r < 4; r++) { mrow[r] = -1e30f; lrow[r] = 0.f; }

    for (int kt = 0; kt < ktmax; kt++) {
        __syncthreads();   // prior iteration's Ks/Vs/Ds reads done
        *(uint4*)((char*)Ks + c0 * 16) = rk0;
        *(uint4*)((char*)Ks + c1 * 16) = rk1;
        *(uint4*)((char*)Vs + c0 * 16) = rv0;
        *(uint4*)((char*)Vs + c1 * 16) = rv1;
#pragma unroll
        for (int j = 0; j < 4; j++)
            DsW[j] = (uint32_t)(dd[j].x & 63) | ((uint32_t)(dd[j].y & 63) << 8) |
                     ((uint32_t)(dd[j].z & 63) << 16) | ((uint32_t)(dd[j].w & 63) << 24);
        __syncthreads();
        if (kt + 1 < ktmax) {
            const u16* kb = kbase + (size_t)(kt + 1) * 64 * 64;
            rk0 = *(const uint4*)(kb + c0 * 8);
            rk1 = *(const uint4*)(kb + c1 * 8);
            rv0 = *(const uint4*)(vbase + (size_t)(c0 >> 3) * 512 + (kt + 1) * 64 + (c0 & 7) * 8);
            rv1 = *(const uint4*)(vbase + (size_t)(c1 >> 3) * 512 + (kt + 1) * 64 + (c1 & 7) * 8);
            const int* dgn = dg + (kt + 1) * 64;
#pragma unroll
            for (int j = 0; j < 4; j++) dd[j] = *(const int4*)(dgn + j * 4);
        }

        f32x4 sacc[4] = {};
#pragma unroll
        for (int ni = 0; ni < 4; ni++) {
            const u16* pK = Ks + (ni * 16 + col16) * 64 + g16 * 8;
            bf16x8 kf0 = *(const bf16x8*)pK;
            bf16x8 kf1 = *(const bf16x8*)(pK + 32);
            sacc[ni] = MFMA16(qa0, kf0, sacc[ni]);
            sacc[ni] = MFMA16(qa1, kf1, sacc[ni]);
        }

        float rmax[4] = {-1e30f, -1e30f, -1e30f, -1e30f};
        const int qrl = wave * 16 + g16 * 4;
#pragma unroll
        for (int ni = 0; ni < 4; ni++) {
            const int kcl = ni * 16 + col16;
            const bool masked = (kt * 64 + kcl) >= len_b;
#pragma unroll
            for (int r = 0; r < 4; r++) {
                float s = sacc[ni][r] + demb[Ds[(qrl + r) * 64 + kcl]];
                s = masked ? -1e9f : s;
                sacc[ni][r] = s;
                rmax[r] = fmaxf(rmax[r], s);
            }
        }
#pragma unroll
        for (int off = 1; off < 16; off <<= 1)
#pragma unroll
            for (int r = 0; r < 4; r++) rmax[r] = fmaxf(rmax[r], __shfl_xor(rmax[r], off));

        float alpha[4], rsum[4];
#pragma unroll
        for (int r = 0; r < 4; r++) {
            float mn = fmaxf(mrow[r], rmax[r]);
            alpha[r] = __expf(mrow[r] - mn);
            mrow[r] = mn;
            rsum[r] = 0.f;
        }
#pragma unroll
        for (int ni = 0; ni < 4; ni++)
#pragma unroll
            for (int r = 0; r < 4; r++) {
                float p = __expf(sacc[ni][r] - mrow[r]);
                sacc[ni][r] = p;
                rsum[r] += p;
            }
#pragma unroll
        for (int off = 1; off < 16; off <<= 1)
#pragma unroll
            for (int r = 0; r < 4; r++) rsum[r] += __shfl_xor(rsum[r], off);
#pragma unroll
        for (int r = 0; r < 4; r++) lrow[r] = lrow[r] * alpha[r] + rsum[r];
#pragma unroll
        for (int di = 0; di < 4; di++)
#pragma unroll
            for (int r = 0; r < 4; r++) oacc[di][r] *= alpha[r];

        // P: C/D layout -> wave-private LDS -> A-frag layout (no barrier needed)
        u16* Pw = &Ps[wave][0];
#pragma unroll
        for (int ni = 0; ni < 4; ni++)
#pragma unroll
            for (int r = 0; r < 4; r++)
                Pw[(g16 * 4 + r) * 64 + ni * 16 + col16] = f2b(sacc[ni][r]);

        const u16* pP = Pw + col16 * 64 + g16 * 8;
        bf16x8 pa0 = *(const bf16x8*)pP;
        bf16x8 pa1 = *(const bf16x8*)(pP + 32);
#pragma unroll
        for (int di = 0; di < 4; di++) {
            const u16* pV = Vs + (di * 16 + col16) * 64 + g16 * 8;
            bf16x8 vf0 = *(const bf16x8*)pV;
            bf16x8 vf1 = *(const bf16x8*)(pV + 32);
            oacc[di] = MFMA16(pa0, vf0, oacc[di]);
            oacc[di] = MFMA16(pa1, vf1, oacc[di]);
        }
    }

#pragma unroll
    for (int di = 0; di < 4; di++)
#pragma unroll
        for (int r = 0; r < 4; r++) {
            const int qrow = qrow_base + r;
            const int d = di * 16 + col16;
            const float inv_l = 1.0f / fmaxf(lrow[r], 1e-30f);
            ctx[(size_t)(b * 512 + qrow) * 1024 + h * 64 + d] = f2b(oacc[di][r] * inv_l);
        }
}

// ---------------------------------------------------------------------------
// Kernel 3: ctx(bf16) @ Wo^T(bf16) + bo -> f32. 64x64 tiles, grid (64,16)
// (m-tile in x: the 16 n-tiles sharing a ctx m-tile land on one XCD).
// ---------------------------------------------------------------------------
__global__ __launch_bounds__(256, 4) void gemm_out_b(
    const u16* __restrict__ ctx, const u16* __restrict__ wob,
    const float* __restrict__ bo, float* __restrict__ out)
{
    __shared__ __align__(16) u16 lA[2][64 * 32];
    __shared__ __align__(16) u16 lB[2][64 * 32];
    const int t = threadIdx.x, wave = t >> 6, lane = t & 63;
    const int m0 = blockIdx.x << 6;
    const int n0 = blockIdx.y << 6;
    const int wr = wave >> 1, wc = wave & 1;
    const int col16 = lane & 15, g16 = lane >> 4;
    f32x4 acc[2][2] = {};

    const int cA = wave * 64 + lane;
    const u16* gA = ctx + (size_t)(m0 + (cA >> 2)) * 1024 + ((cA & 3) << 3);
    const u16* gB = wob + (size_t)(n0 + (cA >> 2)) * 1024 + ((cA & 3) << 3);

    load16(gA, (char*)lA[0] + wave * 1024);
    load16(gB, (char*)lB[0] + wave * 1024);

    for (int it = 0; it < 32; ++it) {
        const int buf = it & 1, nbuf = buf ^ 1;
        __syncthreads();
        if (it + 1 < 32) {
            const int kk = (it + 1) << 5;
            load16(gA + kk, (char*)lA[nbuf] + wave * 1024);
            load16(gB + kk, (char*)lB[nbuf] + wave * 1024);
        }
        const u16* pA = lA[buf] + (wr * 32 + col16) * 32 + g16 * 8;
        const u16* pB = lB[buf] + (wc * 32 + col16) * 32 + g16 * 8;
        bf16x8 af[2], bfr[2];
#pragma unroll
        for (int i = 0; i < 2; i++) {
            af[i]  = *(const bf16x8*)(pA + i * 512);
            bfr[i] = *(const bf16x8*)(pB + i * 512);
        }
#pragma unroll
        for (int mi = 0; mi < 2; mi++)
#pragma unroll
            for (int ni = 0; ni < 2; ni++)
                acc[mi][ni] = MFMA16(af[mi], bfr[ni], acc[mi][ni]);
    }

#pragma unroll
    for (int ni = 0; ni < 2; ni++) {
        const int n = n0 + wc * 32 + ni * 16 + col16;
        const float bn = bo[n];
#pragma unroll
        for (int mi = 0; mi < 2; mi++)
#pragma unroll
            for (int r = 0; r < 4; r++) {
                const int m = m0 + wr * 32 + mi * 16 + g16 * 4 + r;
                out[(size_t)m * 1024 + n] = acc[mi][ni][r] + bn;
            }
    }
}

// ---------------------------------------------------------------------------
// Kernel 3 (fallback): ctx(bf16) @ Wo^T(f32) + bo -> f32 (round-3 path).
// ---------------------------------------------------------------------------
__global__ __launch_bounds__(256) void gemm_out_f32(
    const u16* __restrict__ ctx, const float* __restrict__ Wo,
    const float* __restrict__ bo, float* __restrict__ out)
{
    __shared__ __align__(16) u16 lA[128 * 32];
    __shared__ __align__(16) u16 lB[128 * 32];
    const int t = threadIdx.x, wave = t >> 6, lane = t & 63;
    const int n0 = blockIdx.x << 7;
    const int m0 = blockIdx.y << 7;
    const int wr = wave >> 1, wc = wave & 1;
    const int col16 = lane & 15, g16 = lane >> 4;
    f32x4 acc[4][4] = {};

    const int c0   = wave * 128 + lane;
    const int row0 = c0 >> 2;
    const int kp   = (c0 & 3) << 3;
    const u16* gA = ctx + (size_t)(m0 + row0) * 1024 + kp;
    const size_t gB0 = (size_t)(n0 + row0) * 1024 + kp;
    u16* wA0 = lA + c0 * 8;
    u16* wA1 = lA + (c0 + 64) * 8;
    u16* wB0 = lB + c0 * 8;
    u16* wB1 = lB + (c0 + 64) * 8;

    uint4 ua0 = *(const uint4*)gA;
    uint4 ua1 = *(const uint4*)(gA + 16 * 1024);
    bf16x8 ra0 = *(bf16x8*)&ua0, ra1 = *(bf16x8*)&ua1;
    bf16x8 rb0 = ld8f(Wo + gB0);
    bf16x8 rb1 = ld8f(Wo + gB0 + 16 * 1024);

    for (int kk = 32; kk <= 1024; kk += 32) {
        __syncthreads();
        *(bf16x8*)wA0 = ra0; *(bf16x8*)wA1 = ra1;
        *(bf16x8*)wB0 = rb0; *(bf16x8*)wB1 = rb1;
        __syncthreads();
        if (kk < 1024) {
            uint4 t0 = *(const uint4*)(gA + kk);
            uint4 t1 = *(const uint4*)(gA + kk + 16 * 1024);
            ra0 = *(bf16x8*)&t0; ra1 = *(bf16x8*)&t1;
            rb0 = ld8f(Wo + gB0 + kk);
            rb1 = ld8f(Wo + gB0 + kk + 16 * 1024);
        }
        const u16* pA = lA + (wr * 64 + col16) * 32 + g16 * 8;
        const u16* pB = lB + (wc * 64 + col16) * 32 + g16 * 8;
        bf16x8 af[4], bfr[4];
#pragma unroll
        for (int i = 0; i < 4; i++) {
            af[i]  = *(const bf16x8*)(pA + i * 512);
            bfr[i] = *(const bf16x8*)(pB + i * 512);
        }
#pragma unroll
        for (int mi = 0; mi < 4; mi++)
#pragma unroll
            for (int ni = 0; ni < 4; ni++)
                acc[mi][ni] = MFMA16(af[mi], bfr[ni], acc[mi][ni]);
    }

#pragma unroll
    for (int ni = 0; ni < 4; ni++) {
        const int n = n0 + wc * 64 + ni * 16 + col16;
        const float bn = bo[n];
#pragma unroll
        for (int mi = 0; mi < 4; mi++)
#pragma unroll
            for (int r = 0; r < 4; r++) {
                const int m = m0 + wr * 64 + mi * 16 + g16 * 4 + r;
                out[(size_t)m * 1024 + n] = acc[mi][ni][r] + bn;
            }
    }
}

extern "C" void kernel_launch(void* const* d_in, const int* in_sizes, int n_in,
                              void* d_out, int out_size, void* d_ws, size_t ws_size,
                              hipStream_t stream) {
    const float* q       = (const float*)d_in[0];
    const float* k       = (const float*)d_in[1];
    const float* v       = (const float*)d_in[2];
    const float* Wq      = (const float*)d_in[3];
    const float* bq      = (const float*)d_in[4];
    const float* Wk      = (const float*)d_in[5];
    const float* bk      = (const float*)d_in[6];
    const float* Wv      = (const float*)d_in[7];
    const float* bv      = (const float*)d_in[8];
    const float* Wo      = (const float*)d_in[9];
    const float* bo      = (const float*)d_in[10];
    const float* demb    = (const float*)d_in[11];
    const float* sin_enc = (const float*)d_in[12];
    const int* length    = (const int*)d_in[13];
    const int* dist      = (const int*)d_in[14];

    const size_t SLOT = 4194304;          // 8 MiB region, in u16 elements
    u16* qh  = (u16*)d_ws;
    u16* kh  = qh + SLOT;
    u16* vt  = kh + SLOT;
    u16* ctx = vt + SLOT;

    if (ws_size >= (size_t)64 * 1024 * 1024) {
        u16* qb  = ctx + SLOT;
        u16* kb  = qb + SLOT;
        u16* vb  = kb + SLOT;
        u16* wqb = vb + SLOT;
        u16* wkb = wqb + 1048576;
        u16* wvb = wkb + 1048576;
        u16* wob = wvb + 1048576;
        convert_k<<<dim3(2048, 7), 256, 0, stream>>>(q, k, v, Wq, Wk, Wv, Wo,
                                                     qb, kb, vb, wqb, wkb, wvb, wob);
        gemm_proj_b<<<dim3(192, 8), 256, 0, stream>>>(qb, kb, vb, wqb, wkb, wvb,
                                                      bq, bk, bv, sin_enc, qh, kh, vt);
        attn_kernel<<<dim3(1024), 256, 0, stream>>>(qh, kh, vt, demb, length, dist, ctx);
        gemm_out_b<<<dim3(64, 16), 256, 0, stream>>>(ctx, wob, bo, (float*)d_out);
    } else {
        gemm_proj_f32<<<dim3(24, 32), 256, 0, stream>>>(q, k, v, Wq, bq, Wk, bk, Wv, bv,
                                                        sin_enc, qh, kh, vt);
        attn_kernel<<<dim3(1024), 256, 0, stream>>>(qh, kh, vt, demb, length, dist, ctx);
        gemm_out_f32<<<dim3(8, 32), 256, 0, stream>>>(ctx, Wo, bo, (float*)d_out);
    }
}